// Round 1
// baseline (2301.421 us; speedup 1.0000x reference)
//
#include <hip/hip_runtime.h>
#include <hip/hip_bf16.h>

#define D_MODEL 1024
#define D_STATE 16
#define D_CONV 4
#define D_INNER 2048
#define DT_RANK 64
#define BATCH 2
#define SEQ 2048
#define NROW (BATCH * SEQ)          // 4096
#define XPROJ_N (DT_RANK + 2 * D_STATE)  // 96

// ---------------------------------------------------------------------------
// f32 tiled GEMM: C(MxN) = A(MxK) @ B(KxN), all row-major. BM=BN=128, BK=16.
// 256 threads, 8x8 per thread (split-half fragments for conflict-free LDS).
// ---------------------------------------------------------------------------
__global__ __launch_bounds__(256) void gemm_f32(const float* __restrict__ A,
                                                const float* __restrict__ B,
                                                float* __restrict__ C,
                                                int M, int N, int K) {
    __shared__ float As[16][132];   // [k][m], +4 pad (store conflicts)
    __shared__ float Bs[16][128];   // [k][n]
    const int tid = threadIdx.x;
    const int bm = blockIdx.x * 128;
    const int bn = blockIdx.y * 128;
    const int tx = tid & 15;        // col group
    const int ty = tid >> 4;        // row group

    float acc[8][8];
#pragma unroll
    for (int i = 0; i < 8; ++i)
#pragma unroll
        for (int j = 0; j < 8; ++j) acc[i][j] = 0.f;

    for (int k0 = 0; k0 < K; k0 += 16) {
        // A tile: 128 rows x 16 k = 512 float4, 2 per thread
#pragma unroll
        for (int l = 0; l < 2; ++l) {
            int i = tid + l * 256;
            int r = i >> 2, c4 = (i & 3) << 2;
            float4 v = *(const float4*)(A + (size_t)(bm + r) * K + k0 + c4);
            As[c4 + 0][r] = v.x; As[c4 + 1][r] = v.y;
            As[c4 + 2][r] = v.z; As[c4 + 3][r] = v.w;
        }
        // B tile: 16 rows x 128 n = 512 float4, 2 per thread
#pragma unroll
        for (int l = 0; l < 2; ++l) {
            int i = tid + l * 256;
            int r = i >> 5, c4 = (i & 31) << 2;
            *(float4*)(&Bs[r][c4]) = *(const float4*)(B + (size_t)(k0 + r) * N + bn + c4);
        }
        __syncthreads();
#pragma unroll
        for (int k = 0; k < 16; ++k) {
            float a[8], b[8];
            *(float4*)&a[0] = *(const float4*)&As[k][ty * 4];
            *(float4*)&a[4] = *(const float4*)&As[k][64 + ty * 4];
            *(float4*)&b[0] = *(const float4*)&Bs[k][tx * 4];
            *(float4*)&b[4] = *(const float4*)&Bs[k][64 + tx * 4];
#pragma unroll
            for (int i = 0; i < 8; ++i)
#pragma unroll
                for (int j = 0; j < 8; ++j)
                    acc[i][j] = fmaf(a[i], b[j], acc[i][j]);
        }
        __syncthreads();
    }
#pragma unroll
    for (int i = 0; i < 8; ++i) {
        int r = bm + ((i < 4) ? (ty * 4 + i) : (64 + ty * 4 + (i - 4)));
#pragma unroll
        for (int jh = 0; jh < 2; ++jh) {
            int c = bn + ((jh == 0) ? (tx * 4) : (64 + tx * 4));
            float4 v = make_float4(acc[i][jh * 4 + 0], acc[i][jh * 4 + 1],
                                   acc[i][jh * 4 + 2], acc[i][jh * 4 + 3]);
            *(float4*)(C + (size_t)r * N + c) = v;
        }
    }
}

// ---------------------------------------------------------------------------
// Causal depthwise conv (D_CONV=4) + bias + SiLU.  xz rows are (b*SEQ+t) of
// width 2*D_INNER; we read the first D_INNER cols (xc).
// ---------------------------------------------------------------------------
__global__ __launch_bounds__(256) void conv_silu(const float* __restrict__ xz,
                                                 const float* __restrict__ conv_w,
                                                 const float* __restrict__ conv_b,
                                                 float* __restrict__ xc_act) {
    int idx = blockIdx.x * 256 + threadIdx.x;       // over NROW*D_INNER
    int d = idx & (D_INNER - 1);
    int r = idx >> 11;                               // b*SEQ + t
    int t = r & (SEQ - 1);
    float acc = conv_b[d];
#pragma unroll
    for (int k = 0; k < D_CONV; ++k) {
        int tt = t + k - (D_CONV - 1);
        if (tt >= 0)
            acc = fmaf(xz[(size_t)(r + k - (D_CONV - 1)) * (2 * D_INNER) + d],
                       conv_w[d * D_CONV + k], acc);
    }
    float s = acc / (1.f + __expf(-acc));            // silu
    xc_act[(size_t)r * D_INNER + d] = s;
}

// ---------------------------------------------------------------------------
// x_dbl = xc_act (NROW x D_INNER) @ x_proj_w (D_INNER x 96). BM=32, full N=96.
// ---------------------------------------------------------------------------
__global__ __launch_bounds__(256) void xdbl_gemm(const float* __restrict__ A,
                                                 const float* __restrict__ W,
                                                 float* __restrict__ out) {
    __shared__ float As[32][132];    // [row][k], +4 pad
    __shared__ float Ws[128][96];    // [k][col]
    const int tid = threadIdx.x;
    const int bm = blockIdx.x * 32;
    const int tc = tid & 31;         // cols tc*3 .. +2
    const int tr = tid >> 5;         // rows tr*4 .. +3
    float acc[4][3];
#pragma unroll
    for (int i = 0; i < 4; ++i)
#pragma unroll
        for (int j = 0; j < 3; ++j) acc[i][j] = 0.f;

    for (int k0 = 0; k0 < D_INNER; k0 += 128) {
#pragma unroll
        for (int l = 0; l < 4; ++l) {                 // A tile 32x128
            int i = tid + l * 256;
            int r = i >> 5, c4 = (i & 31) << 2;
            *(float4*)&As[r][c4] = *(const float4*)(A + (size_t)(bm + r) * D_INNER + k0 + c4);
        }
#pragma unroll
        for (int l = 0; l < 12; ++l) {                // W tile 128x96
            int i = tid + l * 256;
            int r = i / 24, c4 = (i % 24) << 2;
            *(float4*)&Ws[r][c4] = *(const float4*)(W + (size_t)(k0 + r) * XPROJ_N + c4);
        }
        __syncthreads();
#pragma unroll 8
        for (int k = 0; k < 128; ++k) {
            float a0 = As[tr * 4 + 0][k], a1 = As[tr * 4 + 1][k];
            float a2 = As[tr * 4 + 2][k], a3 = As[tr * 4 + 3][k];
            float w0 = Ws[k][tc * 3 + 0], w1 = Ws[k][tc * 3 + 1], w2 = Ws[k][tc * 3 + 2];
            acc[0][0] = fmaf(a0, w0, acc[0][0]); acc[0][1] = fmaf(a0, w1, acc[0][1]); acc[0][2] = fmaf(a0, w2, acc[0][2]);
            acc[1][0] = fmaf(a1, w0, acc[1][0]); acc[1][1] = fmaf(a1, w1, acc[1][1]); acc[1][2] = fmaf(a1, w2, acc[1][2]);
            acc[2][0] = fmaf(a2, w0, acc[2][0]); acc[2][1] = fmaf(a2, w1, acc[2][1]); acc[2][2] = fmaf(a2, w2, acc[2][2]);
            acc[3][0] = fmaf(a3, w0, acc[3][0]); acc[3][1] = fmaf(a3, w1, acc[3][1]); acc[3][2] = fmaf(a3, w2, acc[3][2]);
        }
        __syncthreads();
    }
#pragma unroll
    for (int i = 0; i < 4; ++i)
#pragma unroll
        for (int j = 0; j < 3; ++j)
            out[(size_t)(bm + tr * 4 + i) * XPROJ_N + tc * 3 + j] = acc[i][j];
}

// ---------------------------------------------------------------------------
// dlt = softplus(x_dbl[:, :64] @ dt_proj_w + dt_proj_b).  K=64, tiles 64x64.
// ---------------------------------------------------------------------------
__global__ __launch_bounds__(256) void dt_gemm(const float* __restrict__ xdbl,
                                               const float* __restrict__ W,
                                               const float* __restrict__ bias,
                                               float* __restrict__ out) {
    __shared__ float As[64][68];     // [q][row], +4 pad
    __shared__ float Ws[64][64];     // [q][col]
    const int tid = threadIdx.x;
    const int bm = blockIdx.x * 64, bn = blockIdx.y * 64;
#pragma unroll
    for (int l = 0; l < 4; ++l) {    // A: 64 rows x 64 q
        int i = tid + l * 256;
        int r = i >> 4, q4 = (i & 15) << 2;
        float4 v = *(const float4*)(xdbl + (size_t)(bm + r) * XPROJ_N + q4);
        As[q4 + 0][r] = v.x; As[q4 + 1][r] = v.y; As[q4 + 2][r] = v.z; As[q4 + 3][r] = v.w;
    }
#pragma unroll
    for (int l = 0; l < 4; ++l) {    // W: 64 q x 64 cols
        int i = tid + l * 256;
        int q = i >> 4, c4 = (i & 15) << 2;
        *(float4*)&Ws[q][c4] = *(const float4*)(W + (size_t)q * D_INNER + bn + c4);
    }
    __syncthreads();
    const int tx = tid & 15, ty = tid >> 4;
    float acc[4][4];
#pragma unroll
    for (int i = 0; i < 4; ++i)
#pragma unroll
        for (int j = 0; j < 4; ++j) acc[i][j] = 0.f;
#pragma unroll 16
    for (int k = 0; k < 64; ++k) {
        float a[4], w[4];
        *(float4*)a = *(const float4*)&As[k][ty * 4];
        *(float4*)w = *(const float4*)&Ws[k][tx * 4];
#pragma unroll
        for (int i = 0; i < 4; ++i)
#pragma unroll
            for (int j = 0; j < 4; ++j)
                acc[i][j] = fmaf(a[i], w[j], acc[i][j]);
    }
#pragma unroll
    for (int i = 0; i < 4; ++i) {
#pragma unroll
        for (int j = 0; j < 4; ++j) {
            float v = acc[i][j] + bias[bn + tx * 4 + j];
            // softplus, stable: max(v,0) + log1p(exp(-|v|))
            float sp = fmaxf(v, 0.f) + log1pf(__expf(-fabsf(v)));
            out[(size_t)(bm + ty * 4 + i) * D_INNER + bn + tx * 4 + j] = sp;
        }
    }
}

// ---------------------------------------------------------------------------
// Selective scan + skip (xc*D) + z-gating. Thread per (b,d,n); 16-lane groups
// reduce over states via shfl_xor. Writes y_gated in place of dlt (safe:
// same (b,t,d) address, read-before-write within the same thread iteration).
// ---------------------------------------------------------------------------
__global__ __launch_bounds__(256) void scan_kernel(const float* __restrict__ dlt,
                                                   const float* __restrict__ xc,
                                                   const float* __restrict__ xdbl,
                                                   const float* __restrict__ xz,
                                                   const float* __restrict__ A_log,
                                                   const float* __restrict__ Dvec,
                                                   float* __restrict__ ygate) {
    const int tid = threadIdx.x;
    const int n = tid & 15;
    const int gg = blockIdx.x * 16 + (tid >> 4);     // (b, d) group
    const int b = gg >> 11;
    const int d = gg & (D_INNER - 1);

    const float A = -__expf(A_log[d * D_STATE + n]);
    const float Dd = Dvec[d];
    float h = 0.f;

    const float* dlt_p  = dlt + (size_t)b * SEQ * D_INNER + d;
    const float* xc_p   = xc  + (size_t)b * SEQ * D_INNER + d;
    const float* z_p    = xz  + (size_t)b * SEQ * (2 * D_INNER) + D_INNER + d;
    const float* xdbl_p = xdbl + (size_t)b * SEQ * XPROJ_N;
    float* out_p = ygate + (size_t)b * SEQ * D_INNER + d;

    for (int t = 0; t < SEQ; ++t) {
        float dt = dlt_p[(size_t)t * D_INNER];
        float xv = xc_p[(size_t)t * D_INNER];
        float Bn = xdbl_p[t * XPROJ_N + DT_RANK + n];
        float Cn = xdbl_p[t * XPROJ_N + DT_RANK + D_STATE + n];
        float dA = __expf(dt * A);
        h = fmaf(dA, h, dt * xv * Bn);
        float contrib = h * Cn;
        contrib += __shfl_xor(contrib, 1, 64);
        contrib += __shfl_xor(contrib, 2, 64);
        contrib += __shfl_xor(contrib, 4, 64);
        contrib += __shfl_xor(contrib, 8, 64);
        if (n == 0) {
            float zv = z_p[(size_t)t * (2 * D_INNER)];
            float y = contrib + xv * Dd;
            float sz = zv / (1.f + __expf(-zv));
            out_p[(size_t)t * D_INNER] = y * sz;
        }
    }
}

// ---------------------------------------------------------------------------
extern "C" void kernel_launch(void* const* d_in, const int* in_sizes, int n_in,
                              void* d_out, int out_size, void* d_ws, size_t ws_size,
                              hipStream_t stream) {
    const float* x          = (const float*)d_in[0];
    const float* in_proj_w  = (const float*)d_in[1];
    const float* conv_w     = (const float*)d_in[2];
    const float* conv_b     = (const float*)d_in[3];
    const float* x_proj_w   = (const float*)d_in[4];
    const float* dt_proj_w  = (const float*)d_in[5];
    const float* dt_proj_b  = (const float*)d_in[6];
    const float* A_log      = (const float*)d_in[7];
    const float* Dvec       = (const float*)d_in[8];
    const float* out_proj_w = (const float*)d_in[9];
    float* out = (float*)d_out;

    float* xz     = (float*)d_ws;                          // 4096 x 4096
    float* xc_act = xz + (size_t)NROW * 2 * D_INNER;       // 4096 x 2048
    float* x_dbl  = xc_act + (size_t)NROW * D_INNER;       // 4096 x 96
    float* dlt    = x_dbl + (size_t)NROW * XPROJ_N;        // 4096 x 2048 (also y_gated)

    // 1) xz = x @ in_proj_w   (M=4096, N=4096, K=1024)
    gemm_f32<<<dim3(NROW / 128, (2 * D_INNER) / 128), 256, 0, stream>>>(
        x, in_proj_w, xz, NROW, 2 * D_INNER, D_MODEL);
    // 2) conv + silu
    conv_silu<<<(NROW * D_INNER) / 256, 256, 0, stream>>>(xz, conv_w, conv_b, xc_act);
    // 3) x_dbl = xc_act @ x_proj_w
    xdbl_gemm<<<NROW / 32, 256, 0, stream>>>(xc_act, x_proj_w, x_dbl);
    // 4) dlt = softplus(x_dbl[:, :64] @ dt_proj_w + b)
    dt_gemm<<<dim3(NROW / 64, D_INNER / 64), 256, 0, stream>>>(x_dbl, dt_proj_w, dt_proj_b, dlt);
    // 5) selective scan + skip + gate (in-place into dlt)
    scan_kernel<<<(BATCH * D_INNER) / 16, 256, 0, stream>>>(
        dlt, xc_act, x_dbl, xz, A_log, Dvec, dlt);
    // 6) out = y_gated @ out_proj_w  (M=4096, N=1024, K=2048)
    gemm_f32<<<dim3(NROW / 128, D_MODEL / 128), 256, 0, stream>>>(
        dlt, out_proj_w, out, NROW, D_MODEL, D_INNER);
}

// Round 2
// 1267.873 us; speedup vs baseline: 1.8152x; 1.8152x over previous
//
#include <hip/hip_runtime.h>
#include <hip/hip_bf16.h>

#define D_MODEL 1024
#define D_STATE 16
#define D_CONV 4
#define D_INNER 2048
#define DT_RANK 64
#define BATCH 2
#define SEQ 2048
#define NROW (BATCH * SEQ)          // 4096
#define XPROJ_N (DT_RANK + 2 * D_STATE)  // 96
#define TT 64                       // scan time-tile

// ---------------------------------------------------------------------------
// f32 tiled GEMM: C(MxN) = A(MxK) @ B(KxN), all row-major. BM=BN=128, BK=16.
// 256 threads, 8x8 per thread (split-half fragments for conflict-free LDS).
// ---------------------------------------------------------------------------
__global__ __launch_bounds__(256) void gemm_f32(const float* __restrict__ A,
                                                const float* __restrict__ B,
                                                float* __restrict__ C,
                                                int M, int N, int K) {
    __shared__ float As[16][132];   // [k][m], +4 pad (store conflicts)
    __shared__ float Bs[16][128];   // [k][n]
    const int tid = threadIdx.x;
    const int bm = blockIdx.x * 128;
    const int bn = blockIdx.y * 128;
    const int tx = tid & 15;        // col group
    const int ty = tid >> 4;        // row group

    float acc[8][8];
#pragma unroll
    for (int i = 0; i < 8; ++i)
#pragma unroll
        for (int j = 0; j < 8; ++j) acc[i][j] = 0.f;

    for (int k0 = 0; k0 < K; k0 += 16) {
        // A tile: 128 rows x 16 k = 512 float4, 2 per thread
#pragma unroll
        for (int l = 0; l < 2; ++l) {
            int i = tid + l * 256;
            int r = i >> 2, c4 = (i & 3) << 2;
            float4 v = *(const float4*)(A + (size_t)(bm + r) * K + k0 + c4);
            As[c4 + 0][r] = v.x; As[c4 + 1][r] = v.y;
            As[c4 + 2][r] = v.z; As[c4 + 3][r] = v.w;
        }
        // B tile: 16 rows x 128 n = 512 float4, 2 per thread
#pragma unroll
        for (int l = 0; l < 2; ++l) {
            int i = tid + l * 256;
            int r = i >> 5, c4 = (i & 31) << 2;
            *(float4*)(&Bs[r][c4]) = *(const float4*)(B + (size_t)(k0 + r) * N + bn + c4);
        }
        __syncthreads();
#pragma unroll
        for (int k = 0; k < 16; ++k) {
            float a[8], b[8];
            *(float4*)&a[0] = *(const float4*)&As[k][ty * 4];
            *(float4*)&a[4] = *(const float4*)&As[k][64 + ty * 4];
            *(float4*)&b[0] = *(const float4*)&Bs[k][tx * 4];
            *(float4*)&b[4] = *(const float4*)&Bs[k][64 + tx * 4];
#pragma unroll
            for (int i = 0; i < 8; ++i)
#pragma unroll
                for (int j = 0; j < 8; ++j)
                    acc[i][j] = fmaf(a[i], b[j], acc[i][j]);
        }
        __syncthreads();
    }
#pragma unroll
    for (int i = 0; i < 8; ++i) {
        int r = bm + ((i < 4) ? (ty * 4 + i) : (64 + ty * 4 + (i - 4)));
#pragma unroll
        for (int jh = 0; jh < 2; ++jh) {
            int c = bn + ((jh == 0) ? (tx * 4) : (64 + tx * 4));
            float4 v = make_float4(acc[i][jh * 4 + 0], acc[i][jh * 4 + 1],
                                   acc[i][jh * 4 + 2], acc[i][jh * 4 + 3]);
            *(float4*)(C + (size_t)r * N + c) = v;
        }
    }
}

// ---------------------------------------------------------------------------
// Causal depthwise conv (D_CONV=4) + bias + SiLU.
// ---------------------------------------------------------------------------
__global__ __launch_bounds__(256) void conv_silu(const float* __restrict__ xz,
                                                 const float* __restrict__ conv_w,
                                                 const float* __restrict__ conv_b,
                                                 float* __restrict__ xc_act) {
    int idx = blockIdx.x * 256 + threadIdx.x;       // over NROW*D_INNER
    int d = idx & (D_INNER - 1);
    int r = idx >> 11;                               // b*SEQ + t
    int t = r & (SEQ - 1);
    float acc = conv_b[d];
#pragma unroll
    for (int k = 0; k < D_CONV; ++k) {
        int tt = t + k - (D_CONV - 1);
        if (tt >= 0)
            acc = fmaf(xz[(size_t)(r + k - (D_CONV - 1)) * (2 * D_INNER) + d],
                       conv_w[d * D_CONV + k], acc);
    }
    float s = acc / (1.f + __expf(-acc));            // silu
    xc_act[(size_t)r * D_INNER + d] = s;
}

// ---------------------------------------------------------------------------
// x_dbl = xc_act (NROW x D_INNER) @ x_proj_w (D_INNER x 96). BM=32, full N=96.
// ---------------------------------------------------------------------------
__global__ __launch_bounds__(256) void xdbl_gemm(const float* __restrict__ A,
                                                 const float* __restrict__ W,
                                                 float* __restrict__ out) {
    __shared__ float As[32][132];    // [row][k], +4 pad
    __shared__ float Ws[128][96];    // [k][col]
    const int tid = threadIdx.x;
    const int bm = blockIdx.x * 32;
    const int tc = tid & 31;         // cols tc*3 .. +2
    const int tr = tid >> 5;         // rows tr*4 .. +3
    float acc[4][3];
#pragma unroll
    for (int i = 0; i < 4; ++i)
#pragma unroll
        for (int j = 0; j < 3; ++j) acc[i][j] = 0.f;

    for (int k0 = 0; k0 < D_INNER; k0 += 128) {
#pragma unroll
        for (int l = 0; l < 4; ++l) {                 // A tile 32x128
            int i = tid + l * 256;
            int r = i >> 5, c4 = (i & 31) << 2;
            *(float4*)&As[r][c4] = *(const float4*)(A + (size_t)(bm + r) * D_INNER + k0 + c4);
        }
#pragma unroll
        for (int l = 0; l < 12; ++l) {                // W tile 128x96
            int i = tid + l * 256;
            int r = i / 24, c4 = (i % 24) << 2;
            *(float4*)&Ws[r][c4] = *(const float4*)(W + (size_t)(k0 + r) * XPROJ_N + c4);
        }
        __syncthreads();
#pragma unroll 8
        for (int k = 0; k < 128; ++k) {
            float a0 = As[tr * 4 + 0][k], a1 = As[tr * 4 + 1][k];
            float a2 = As[tr * 4 + 2][k], a3 = As[tr * 4 + 3][k];
            float w0 = Ws[k][tc * 3 + 0], w1 = Ws[k][tc * 3 + 1], w2 = Ws[k][tc * 3 + 2];
            acc[0][0] = fmaf(a0, w0, acc[0][0]); acc[0][1] = fmaf(a0, w1, acc[0][1]); acc[0][2] = fmaf(a0, w2, acc[0][2]);
            acc[1][0] = fmaf(a1, w0, acc[1][0]); acc[1][1] = fmaf(a1, w1, acc[1][1]); acc[1][2] = fmaf(a1, w2, acc[1][2]);
            acc[2][0] = fmaf(a2, w0, acc[2][0]); acc[2][1] = fmaf(a2, w1, acc[2][1]); acc[2][2] = fmaf(a2, w2, acc[2][2]);
            acc[3][0] = fmaf(a3, w0, acc[3][0]); acc[3][1] = fmaf(a3, w1, acc[3][1]); acc[3][2] = fmaf(a3, w2, acc[3][2]);
        }
        __syncthreads();
    }
#pragma unroll
    for (int i = 0; i < 4; ++i)
#pragma unroll
        for (int j = 0; j < 3; ++j)
            out[(size_t)(bm + tr * 4 + i) * XPROJ_N + tc * 3 + j] = acc[i][j];
}

// ---------------------------------------------------------------------------
// dlt = softplus(x_dbl[:, :64] @ dt_proj_w + dt_proj_b).  K=64, tiles 64x64.
// ---------------------------------------------------------------------------
__global__ __launch_bounds__(256) void dt_gemm(const float* __restrict__ xdbl,
                                               const float* __restrict__ W,
                                               const float* __restrict__ bias,
                                               float* __restrict__ out) {
    __shared__ float As[64][68];     // [q][row], +4 pad
    __shared__ float Ws[64][64];     // [q][col]
    const int tid = threadIdx.x;
    const int bm = blockIdx.x * 64, bn = blockIdx.y * 64;
#pragma unroll
    for (int l = 0; l < 4; ++l) {    // A: 64 rows x 64 q
        int i = tid + l * 256;
        int r = i >> 4, q4 = (i & 15) << 2;
        float4 v = *(const float4*)(xdbl + (size_t)(bm + r) * XPROJ_N + q4);
        As[q4 + 0][r] = v.x; As[q4 + 1][r] = v.y; As[q4 + 2][r] = v.z; As[q4 + 3][r] = v.w;
    }
#pragma unroll
    for (int l = 0; l < 4; ++l) {    // W: 64 q x 64 cols
        int i = tid + l * 256;
        int q = i >> 4, c4 = (i & 15) << 2;
        *(float4*)&Ws[q][c4] = *(const float4*)(W + (size_t)q * D_INNER + bn + c4);
    }
    __syncthreads();
    const int tx = tid & 15, ty = tid >> 4;
    float acc[4][4];
#pragma unroll
    for (int i = 0; i < 4; ++i)
#pragma unroll
        for (int j = 0; j < 4; ++j) acc[i][j] = 0.f;
#pragma unroll 16
    for (int k = 0; k < 64; ++k) {
        float a[4], w[4];
        *(float4*)a = *(const float4*)&As[k][ty * 4];
        *(float4*)w = *(const float4*)&Ws[k][tx * 4];
#pragma unroll
        for (int i = 0; i < 4; ++i)
#pragma unroll
            for (int j = 0; j < 4; ++j)
                acc[i][j] = fmaf(a[i], w[j], acc[i][j]);
    }
#pragma unroll
    for (int i = 0; i < 4; ++i) {
#pragma unroll
        for (int j = 0; j < 4; ++j) {
            float v = acc[i][j] + bias[bn + tx * 4 + j];
            float sp = fmaxf(v, 0.f) + log1pf(__expf(-fabsf(v)));
            out[(size_t)(bm + ty * 4 + i) * D_INNER + bn + tx * 4 + j] = sp;
        }
    }
}

// ---------------------------------------------------------------------------
// Selective scan v2: time-tiled, LDS-staged cooperative scan.
// Block = 256 threads = 16 d-channels x 16 states. Grid = B * D_INNER/16.
// Per tile of TT=64 steps:
//   phase 1: coalesced load of dlt/xc (per-d) and B/C (shared) into LDS
//   phase 2: scan from LDS (float4 batched reads, exp2, shfl reduce over n)
//   phase 3: coalesced write-out with fused +xc*D (done in phase 2) and z-gate
// Writes y_gated in place of dlt (tile rows fully read before written).
// ---------------------------------------------------------------------------
__global__ __launch_bounds__(256) void scan_kernel(const float* __restrict__ dlt,
                                                   const float* __restrict__ xc,
                                                   const float* __restrict__ xdbl,
                                                   const float* __restrict__ xz,
                                                   const float* __restrict__ A_log,
                                                   const float* __restrict__ Dvec,
                                                   float* __restrict__ ygate) {
    __shared__ float s_dt[16][TT + 4];   // [d_local][t], stride 68 (16B aligned)
    __shared__ float s_xv[16][TT + 4];
    __shared__ float s_B[16][TT + 4];    // [n][t]
    __shared__ float s_C[16][TT + 4];
    __shared__ float s_y[16][TT + 4];    // [d_local][t]

    const int tid = threadIdx.x;
    const int n  = tid & 15;             // state index (scan phase)
    const int dl = tid >> 4;             // d channel  (scan phase)
    const int b  = blockIdx.x >> 7;      // / (D_INNER/16)
    const int d0 = (blockIdx.x & 127) << 4;
    const int d  = d0 + dl;

    // A2 = A * log2(e)  so dA = exp2(dt * A2)
    const float A2 = -__expf(A_log[d * D_STATE + n]) * 1.44269504f;
    const float Dd = Dvec[d];
    float h = 0.f;

    const size_t rowbase = (size_t)b * SEQ;
    // load-phase thread mapping (d fastest for coalescing)
    const int ld_d = tid & 15, ld_t = tid >> 4;      // 16 t-rows per pass
    const int bc_c = tid & 31, bc_t = tid >> 5;      // 8 t-rows per pass

    for (int t0 = 0; t0 < SEQ; t0 += TT) {
        // ---- phase 1: load ----
#pragma unroll
        for (int p = 0; p < TT / 16; ++p) {
            int t = ld_t + p * 16;
            size_t g = (rowbase + t0 + t) * (size_t)D_INNER + d0 + ld_d;
            s_dt[ld_d][t] = dlt[g];
            s_xv[ld_d][t] = xc[g];
        }
#pragma unroll
        for (int p = 0; p < TT / 8; ++p) {
            int t = bc_t + p * 8;
            float v = xdbl[(rowbase + t0 + t) * (size_t)XPROJ_N + DT_RANK + bc_c];
            if (bc_c < 16) s_B[bc_c][t] = v;
            else           s_C[bc_c - 16][t] = v;
        }
        __syncthreads();

        // ---- phase 2: scan ----
        for (int t = 0; t < TT; t += 4) {
            float dtv[4], xvv[4], Bv[4], Cv[4];
            *(float4*)dtv = *(const float4*)&s_dt[dl][t];
            *(float4*)xvv = *(const float4*)&s_xv[dl][t];
            *(float4*)Bv  = *(const float4*)&s_B[n][t];
            *(float4*)Cv  = *(const float4*)&s_C[n][t];
#pragma unroll
            for (int s = 0; s < 4; ++s) {
                float dA = exp2f(dtv[s] * A2);
                h = fmaf(dA, h, (dtv[s] * xvv[s]) * Bv[s]);
                float c = h * Cv[s];
                c += __shfl_xor(c, 1, 64);
                c += __shfl_xor(c, 2, 64);
                c += __shfl_xor(c, 4, 64);
                c += __shfl_xor(c, 8, 64);
                if (n == 0) s_y[dl][t + s] = fmaf(xvv[s], Dd, c);
            }
        }
        __syncthreads();

        // ---- phase 3: write-out with z-gating ----
#pragma unroll
        for (int p = 0; p < TT / 16; ++p) {
            int t = ld_t + p * 16;
            size_t row = rowbase + t0 + t;
            float zv = xz[row * (size_t)(2 * D_INNER) + D_INNER + d0 + ld_d];
            float y = s_y[ld_d][t];
            float sz = zv / (1.f + __expf(-zv));
            ygate[row * (size_t)D_INNER + d0 + ld_d] = y * sz;
        }
        __syncthreads();   // protect s_* before next tile's load
    }
}

// ---------------------------------------------------------------------------
extern "C" void kernel_launch(void* const* d_in, const int* in_sizes, int n_in,
                              void* d_out, int out_size, void* d_ws, size_t ws_size,
                              hipStream_t stream) {
    const float* x          = (const float*)d_in[0];
    const float* in_proj_w  = (const float*)d_in[1];
    const float* conv_w     = (const float*)d_in[2];
    const float* conv_b     = (const float*)d_in[3];
    const float* x_proj_w   = (const float*)d_in[4];
    const float* dt_proj_w  = (const float*)d_in[5];
    const float* dt_proj_b  = (const float*)d_in[6];
    const float* A_log      = (const float*)d_in[7];
    const float* Dvec       = (const float*)d_in[8];
    const float* out_proj_w = (const float*)d_in[9];
    float* out = (float*)d_out;

    float* xz     = (float*)d_ws;                          // 4096 x 4096
    float* xc_act = xz + (size_t)NROW * 2 * D_INNER;       // 4096 x 2048
    float* x_dbl  = xc_act + (size_t)NROW * D_INNER;       // 4096 x 96
    float* dlt    = x_dbl + (size_t)NROW * XPROJ_N;        // 4096 x 2048 (also y_gated)

    // 1) xz = x @ in_proj_w   (M=4096, N=4096, K=1024)
    gemm_f32<<<dim3(NROW / 128, (2 * D_INNER) / 128), 256, 0, stream>>>(
        x, in_proj_w, xz, NROW, 2 * D_INNER, D_MODEL);
    // 2) conv + silu
    conv_silu<<<(NROW * D_INNER) / 256, 256, 0, stream>>>(xz, conv_w, conv_b, xc_act);
    // 3) x_dbl = xc_act @ x_proj_w
    xdbl_gemm<<<NROW / 32, 256, 0, stream>>>(xc_act, x_proj_w, x_dbl);
    // 4) dlt = softplus(x_dbl[:, :64] @ dt_proj_w + b)
    dt_gemm<<<dim3(NROW / 64, D_INNER / 64), 256, 0, stream>>>(x_dbl, dt_proj_w, dt_proj_b, dlt);
    // 5) selective scan + skip + gate (in-place into dlt)
    scan_kernel<<<BATCH * (D_INNER / 16), 256, 0, stream>>>(
        dlt, xc_act, x_dbl, xz, A_log, Dvec, dlt);
    // 6) out = y_gated @ out_proj_w  (M=4096, N=1024, K=2048)
    gemm_f32<<<dim3(NROW / 128, D_MODEL / 128), 256, 0, stream>>>(
        dlt, out_proj_w, out, NROW, D_MODEL, D_INNER);
}

// Round 3
// 868.181 us; speedup vs baseline: 2.6509x; 1.4604x over previous
//
#include <hip/hip_runtime.h>
#include <hip/hip_bf16.h>

#define D_MODEL 1024
#define D_STATE 16
#define D_CONV 4
#define D_INNER 2048
#define DT_RANK 64
#define BATCH 2
#define SEQ 2048
#define NROW (BATCH * SEQ)          // 4096
#define XPROJ_N (DT_RANK + 2 * D_STATE)  // 96
#define NCHUNK 64                   // time chunks for scan decomposition
#define CL 32                       // SEQ / NCHUNK

// ---------------------------------------------------------------------------
// f32 tiled GEMM: C(MxN) = A(MxK) @ B(KxN), all row-major. BM=BN=128, BK=16.
// ---------------------------------------------------------------------------
__global__ __launch_bounds__(256) void gemm_f32(const float* __restrict__ A,
                                                const float* __restrict__ B,
                                                float* __restrict__ C,
                                                int M, int N, int K) {
    __shared__ float As[16][132];   // [k][m], +4 pad (store conflicts)
    __shared__ float Bs[16][128];   // [k][n]
    const int tid = threadIdx.x;
    const int bm = blockIdx.x * 128;
    const int bn = blockIdx.y * 128;
    const int tx = tid & 15;        // col group
    const int ty = tid >> 4;        // row group

    float acc[8][8];
#pragma unroll
    for (int i = 0; i < 8; ++i)
#pragma unroll
        for (int j = 0; j < 8; ++j) acc[i][j] = 0.f;

    for (int k0 = 0; k0 < K; k0 += 16) {
#pragma unroll
        for (int l = 0; l < 2; ++l) {
            int i = tid + l * 256;
            int r = i >> 2, c4 = (i & 3) << 2;
            float4 v = *(const float4*)(A + (size_t)(bm + r) * K + k0 + c4);
            As[c4 + 0][r] = v.x; As[c4 + 1][r] = v.y;
            As[c4 + 2][r] = v.z; As[c4 + 3][r] = v.w;
        }
#pragma unroll
        for (int l = 0; l < 2; ++l) {
            int i = tid + l * 256;
            int r = i >> 5, c4 = (i & 31) << 2;
            *(float4*)(&Bs[r][c4]) = *(const float4*)(B + (size_t)(k0 + r) * N + bn + c4);
        }
        __syncthreads();
#pragma unroll
        for (int k = 0; k < 16; ++k) {
            float a[8], b[8];
            *(float4*)&a[0] = *(const float4*)&As[k][ty * 4];
            *(float4*)&a[4] = *(const float4*)&As[k][64 + ty * 4];
            *(float4*)&b[0] = *(const float4*)&Bs[k][tx * 4];
            *(float4*)&b[4] = *(const float4*)&Bs[k][64 + tx * 4];
#pragma unroll
            for (int i = 0; i < 8; ++i)
#pragma unroll
                for (int j = 0; j < 8; ++j)
                    acc[i][j] = fmaf(a[i], b[j], acc[i][j]);
        }
        __syncthreads();
    }
#pragma unroll
    for (int i = 0; i < 8; ++i) {
        int r = bm + ((i < 4) ? (ty * 4 + i) : (64 + ty * 4 + (i - 4)));
#pragma unroll
        for (int jh = 0; jh < 2; ++jh) {
            int c = bn + ((jh == 0) ? (tx * 4) : (64 + tx * 4));
            float4 v = make_float4(acc[i][jh * 4 + 0], acc[i][jh * 4 + 1],
                                   acc[i][jh * 4 + 2], acc[i][jh * 4 + 3]);
            *(float4*)(C + (size_t)r * N + c) = v;
        }
    }
}

// ---------------------------------------------------------------------------
// Causal depthwise conv (D_CONV=4) + bias + SiLU.
// ---------------------------------------------------------------------------
__global__ __launch_bounds__(256) void conv_silu(const float* __restrict__ xz,
                                                 const float* __restrict__ conv_w,
                                                 const float* __restrict__ conv_b,
                                                 float* __restrict__ xc_act) {
    int idx = blockIdx.x * 256 + threadIdx.x;       // over NROW*D_INNER
    int d = idx & (D_INNER - 1);
    int r = idx >> 11;                               // b*SEQ + t
    int t = r & (SEQ - 1);
    float acc = conv_b[d];
#pragma unroll
    for (int k = 0; k < D_CONV; ++k) {
        int tt = t + k - (D_CONV - 1);
        if (tt >= 0)
            acc = fmaf(xz[(size_t)(r + k - (D_CONV - 1)) * (2 * D_INNER) + d],
                       conv_w[d * D_CONV + k], acc);
    }
    float s = acc / (1.f + __expf(-acc));            // silu
    xc_act[(size_t)r * D_INNER + d] = s;
}

// ---------------------------------------------------------------------------
// x_dbl = xc_act (NROW x D_INNER) @ x_proj_w (D_INNER x 96). BM=32, full N=96.
// ---------------------------------------------------------------------------
__global__ __launch_bounds__(256) void xdbl_gemm(const float* __restrict__ A,
                                                 const float* __restrict__ W,
                                                 float* __restrict__ out) {
    __shared__ float As[32][132];    // [row][k], +4 pad
    __shared__ float Ws[128][96];    // [k][col]
    const int tid = threadIdx.x;
    const int bm = blockIdx.x * 32;
    const int tc = tid & 31;         // cols tc*3 .. +2
    const int tr = tid >> 5;         // rows tr*4 .. +3
    float acc[4][3];
#pragma unroll
    for (int i = 0; i < 4; ++i)
#pragma unroll
        for (int j = 0; j < 3; ++j) acc[i][j] = 0.f;

    for (int k0 = 0; k0 < D_INNER; k0 += 128) {
#pragma unroll
        for (int l = 0; l < 4; ++l) {                 // A tile 32x128
            int i = tid + l * 256;
            int r = i >> 5, c4 = (i & 31) << 2;
            *(float4*)&As[r][c4] = *(const float4*)(A + (size_t)(bm + r) * D_INNER + k0 + c4);
        }
#pragma unroll
        for (int l = 0; l < 12; ++l) {                // W tile 128x96
            int i = tid + l * 256;
            int r = i / 24, c4 = (i % 24) << 2;
            *(float4*)&Ws[r][c4] = *(const float4*)(W + (size_t)(k0 + r) * XPROJ_N + c4);
        }
        __syncthreads();
#pragma unroll 8
        for (int k = 0; k < 128; ++k) {
            float a0 = As[tr * 4 + 0][k], a1 = As[tr * 4 + 1][k];
            float a2 = As[tr * 4 + 2][k], a3 = As[tr * 4 + 3][k];
            float w0 = Ws[k][tc * 3 + 0], w1 = Ws[k][tc * 3 + 1], w2 = Ws[k][tc * 3 + 2];
            acc[0][0] = fmaf(a0, w0, acc[0][0]); acc[0][1] = fmaf(a0, w1, acc[0][1]); acc[0][2] = fmaf(a0, w2, acc[0][2]);
            acc[1][0] = fmaf(a1, w0, acc[1][0]); acc[1][1] = fmaf(a1, w1, acc[1][1]); acc[1][2] = fmaf(a1, w2, acc[1][2]);
            acc[2][0] = fmaf(a2, w0, acc[2][0]); acc[2][1] = fmaf(a2, w1, acc[2][1]); acc[2][2] = fmaf(a2, w2, acc[2][2]);
            acc[3][0] = fmaf(a3, w0, acc[3][0]); acc[3][1] = fmaf(a3, w1, acc[3][1]); acc[3][2] = fmaf(a3, w2, acc[3][2]);
        }
        __syncthreads();
    }
#pragma unroll
    for (int i = 0; i < 4; ++i)
#pragma unroll
        for (int j = 0; j < 3; ++j)
            out[(size_t)(bm + tr * 4 + i) * XPROJ_N + tc * 3 + j] = acc[i][j];
}

// ---------------------------------------------------------------------------
// dlt = softplus(x_dbl[:, :64] @ dt_proj_w + dt_proj_b).  K=64, tiles 64x64.
// ---------------------------------------------------------------------------
__global__ __launch_bounds__(256) void dt_gemm(const float* __restrict__ xdbl,
                                               const float* __restrict__ W,
                                               const float* __restrict__ bias,
                                               float* __restrict__ out) {
    __shared__ float As[64][68];     // [q][row], +4 pad
    __shared__ float Ws[64][64];     // [q][col]
    const int tid = threadIdx.x;
    const int bm = blockIdx.x * 64, bn = blockIdx.y * 64;
#pragma unroll
    for (int l = 0; l < 4; ++l) {    // A: 64 rows x 64 q
        int i = tid + l * 256;
        int r = i >> 4, q4 = (i & 15) << 2;
        float4 v = *(const float4*)(xdbl + (size_t)(bm + r) * XPROJ_N + q4);
        As[q4 + 0][r] = v.x; As[q4 + 1][r] = v.y; As[q4 + 2][r] = v.z; As[q4 + 3][r] = v.w;
    }
#pragma unroll
    for (int l = 0; l < 4; ++l) {    // W: 64 q x 64 cols
        int i = tid + l * 256;
        int q = i >> 4, c4 = (i & 15) << 2;
        *(float4*)&Ws[q][c4] = *(const float4*)(W + (size_t)q * D_INNER + bn + c4);
    }
    __syncthreads();
    const int tx = tid & 15, ty = tid >> 4;
    float acc[4][4];
#pragma unroll
    for (int i = 0; i < 4; ++i)
#pragma unroll
        for (int j = 0; j < 4; ++j) acc[i][j] = 0.f;
#pragma unroll 16
    for (int k = 0; k < 64; ++k) {
        float a[4], w[4];
        *(float4*)a = *(const float4*)&As[k][ty * 4];
        *(float4*)w = *(const float4*)&Ws[k][tx * 4];
#pragma unroll
        for (int i = 0; i < 4; ++i)
#pragma unroll
            for (int j = 0; j < 4; ++j)
                acc[i][j] = fmaf(a[i], w[j], acc[i][j]);
    }
#pragma unroll
    for (int i = 0; i < 4; ++i) {
#pragma unroll
        for (int j = 0; j < 4; ++j) {
            float v = acc[i][j] + bias[bn + tx * 4 + j];
            float sp = fmaxf(v, 0.f) + log1pf(__expf(-fabsf(v)));
            out[(size_t)(bm + ty * 4 + i) * D_INNER + bn + tx * 4 + j] = sp;
        }
    }
}

// ---------------------------------------------------------------------------
// Selective scan v3: chunked (Blelloch-style) decomposition, h[16] in VGPRs.
// Carry storage lives in the dead xc-half of xz (cols 0..2047): coalescing-
// preserving hole mapping  addr(i) = (i>>11)*4096 + (i&2047).
//   pA  at i in [0, 1<<22)          (rows    0..2047)
//   hc  at i in [1<<22, 1<<23)      (rows 2048..4095)  (h_end, then h_in)
// ---------------------------------------------------------------------------
__device__ __forceinline__ size_t hole(size_t i) {
    return (i >> 11) * 4096 + (i & 2047);
}

// pass 1: per (b, chunk, d): chunk-local h_end[16] and prodA[16]
__global__ __launch_bounds__(256) void scan_pass1(const float* __restrict__ dlt,
                                                  const float* __restrict__ xc,
                                                  const float* __restrict__ xdbl,
                                                  const float* __restrict__ A_log,
                                                  float* __restrict__ carry) {
    __shared__ float s_B[CL][16];
    const int tid = threadIdx.x;
    const int bid = blockIdx.x;              // b*512 + c*8 + dg
    const int dg = bid & 7;
    const int c  = (bid >> 3) & (NCHUNK - 1);
    const int b  = bid >> 9;
    const int d  = dg * 256 + tid;
    const size_t rowbase = (size_t)b * SEQ + c * CL;

    float An[16];
    {
        float4 a0 = *(const float4*)&A_log[d * 16 + 0];
        float4 a1 = *(const float4*)&A_log[d * 16 + 4];
        float4 a2 = *(const float4*)&A_log[d * 16 + 8];
        float4 a3 = *(const float4*)&A_log[d * 16 + 12];
        float tmp[16];
        *(float4*)&tmp[0] = a0; *(float4*)&tmp[4] = a1;
        *(float4*)&tmp[8] = a2; *(float4*)&tmp[12] = a3;
#pragma unroll
        for (int n = 0; n < 16; ++n) An[n] = -__expf(tmp[n]);
    }

    // stage B tile (CL x 16)
#pragma unroll
    for (int p = 0; p < CL * 16 / 256; ++p) {
        int i = tid + p * 256;
        int t = i >> 4, n = i & 15;
        s_B[t][n] = xdbl[(rowbase + t) * (size_t)XPROJ_N + DT_RANK + n];
    }
    __syncthreads();

    float h[16], pA[16];
#pragma unroll
    for (int n = 0; n < 16; ++n) { h[n] = 0.f; pA[n] = 1.f; }

    const float* dtp = dlt + rowbase * D_INNER + d;
    const float* xvp = xc + rowbase * D_INNER + d;

    for (int tb = 0; tb < CL; tb += 4) {
        float dtv[4], xvv[4];
#pragma unroll
        for (int s = 0; s < 4; ++s) {
            dtv[s] = dtp[(size_t)(tb + s) * D_INNER];
            xvv[s] = xvp[(size_t)(tb + s) * D_INNER];
        }
#pragma unroll
        for (int s = 0; s < 4; ++s) {
            float Bv[16];
            *(float4*)&Bv[0]  = *(const float4*)&s_B[tb + s][0];
            *(float4*)&Bv[4]  = *(const float4*)&s_B[tb + s][4];
            *(float4*)&Bv[8]  = *(const float4*)&s_B[tb + s][8];
            *(float4*)&Bv[12] = *(const float4*)&s_B[tb + s][12];
            float du = dtv[s] * xvv[s];
#pragma unroll
            for (int n = 0; n < 16; ++n) {
                float dA = __expf(dtv[s] * An[n]);
                pA[n] *= dA;
                h[n] = fmaf(dA, h[n], du * Bv[n]);
            }
        }
    }

    size_t ci = (((size_t)b * NCHUNK + c) * D_INNER + d) * 16;   // mult of 16
    float* pp = carry + hole(ci);
    float* hp = carry + hole(ci + ((size_t)1 << 22));
    *(float4*)&pp[0]  = *(float4*)&pA[0];  *(float4*)&pp[4]  = *(float4*)&pA[4];
    *(float4*)&pp[8]  = *(float4*)&pA[8];  *(float4*)&pp[12] = *(float4*)&pA[12];
    *(float4*)&hp[0]  = *(float4*)&h[0];   *(float4*)&hp[4]  = *(float4*)&h[4];
    *(float4*)&hp[8]  = *(float4*)&h[8];   *(float4*)&hp[12] = *(float4*)&h[12];
}

// pass 2: per (b,d,n): serial scan over chunk carries; hc becomes h_in.
__global__ __launch_bounds__(256) void scan_pass2(float* __restrict__ carry) {
    int idx = blockIdx.x * 256 + threadIdx.x;        // over B*D*16 = 65536
    int n = idx & 15;
    int d = (idx >> 4) & (D_INNER - 1);
    int b = idx >> 15;
    float prev = 0.f;
    for (int c = 0; c < NCHUNK; ++c) {
        size_t ci = (((size_t)b * NCHUNK + c) * D_INNER + d) * 16 + n;
        size_t op = hole(ci);
        size_t oh = op + (size_t)2048 * 4096;        // +1<<22 elements
        float p = carry[op];
        float e = carry[oh];
        carry[oh] = prev;                            // h_in for chunk c
        prev = fmaf(p, prev, e);
    }
}

// pass 3: re-run chunk with true h_in; y = <h,C> + xv*D; gate with silu(z).
__global__ __launch_bounds__(256) void scan_pass3(const float* __restrict__ dlt,
                                                  const float* __restrict__ xc,
                                                  const float* __restrict__ xdbl,
                                                  const float* __restrict__ xz,
                                                  const float* __restrict__ A_log,
                                                  const float* __restrict__ Dvec,
                                                  const float* __restrict__ carry,
                                                  float* __restrict__ ygate) {
    __shared__ float s_B[CL][16];
    __shared__ float s_C[CL][16];
    const int tid = threadIdx.x;
    const int bid = blockIdx.x;
    const int dg = bid & 7;
    const int c  = (bid >> 3) & (NCHUNK - 1);
    const int b  = bid >> 9;
    const int d  = dg * 256 + tid;
    const size_t rowbase = (size_t)b * SEQ + c * CL;

    float An[16];
    {
        float tmp[16];
        *(float4*)&tmp[0]  = *(const float4*)&A_log[d * 16 + 0];
        *(float4*)&tmp[4]  = *(const float4*)&A_log[d * 16 + 4];
        *(float4*)&tmp[8]  = *(const float4*)&A_log[d * 16 + 8];
        *(float4*)&tmp[12] = *(const float4*)&A_log[d * 16 + 12];
#pragma unroll
        for (int n = 0; n < 16; ++n) An[n] = -__expf(tmp[n]);
    }
    const float Dd = Dvec[d];

    // stage B and C tiles (CL x 16 each)
#pragma unroll
    for (int p = 0; p < CL * 32 / 256; ++p) {
        int i = tid + p * 256;
        int t = i >> 5, col = i & 31;
        float v = xdbl[(rowbase + t) * (size_t)XPROJ_N + DT_RANK + col];
        if (col < 16) s_B[t][col] = v;
        else          s_C[t][col - 16] = v;
    }
    __syncthreads();

    // h_in from carries
    float h[16];
    {
        size_t ci = (((size_t)b * NCHUNK + c) * D_INNER + d) * 16;
        const float* hp = carry + hole(ci + ((size_t)1 << 22));
        *(float4*)&h[0]  = *(const float4*)&hp[0];
        *(float4*)&h[4]  = *(const float4*)&hp[4];
        *(float4*)&h[8]  = *(const float4*)&hp[8];
        *(float4*)&h[12] = *(const float4*)&hp[12];
    }

    const float* dtp = dlt + rowbase * D_INNER + d;
    const float* xvp = xc + rowbase * D_INNER + d;
    const float* zp  = xz + rowbase * (size_t)(2 * D_INNER) + D_INNER + d;
    float* yp = ygate + rowbase * D_INNER + d;

    for (int tb = 0; tb < CL; tb += 4) {
        float dtv[4], xvv[4], zv[4];
#pragma unroll
        for (int s = 0; s < 4; ++s) {
            dtv[s] = dtp[(size_t)(tb + s) * D_INNER];
            xvv[s] = xvp[(size_t)(tb + s) * D_INNER];
            zv[s]  = zp[(size_t)(tb + s) * (2 * D_INNER)];
        }
#pragma unroll
        for (int s = 0; s < 4; ++s) {
            float Bv[16], Cv[16];
            *(float4*)&Bv[0]  = *(const float4*)&s_B[tb + s][0];
            *(float4*)&Bv[4]  = *(const float4*)&s_B[tb + s][4];
            *(float4*)&Bv[8]  = *(const float4*)&s_B[tb + s][8];
            *(float4*)&Bv[12] = *(const float4*)&s_B[tb + s][12];
            *(float4*)&Cv[0]  = *(const float4*)&s_C[tb + s][0];
            *(float4*)&Cv[4]  = *(const float4*)&s_C[tb + s][4];
            *(float4*)&Cv[8]  = *(const float4*)&s_C[tb + s][8];
            *(float4*)&Cv[12] = *(const float4*)&s_C[tb + s][12];
            float du = dtv[s] * xvv[s];
            float y = 0.f;
#pragma unroll
            for (int n = 0; n < 16; ++n) {
                float dA = __expf(dtv[s] * An[n]);
                h[n] = fmaf(dA, h[n], du * Bv[n]);
                y = fmaf(h[n], Cv[n], y);
            }
            y = fmaf(xvv[s], Dd, y);
            float sz = zv[s] / (1.f + __expf(-zv[s]));
            yp[(size_t)(tb + s) * D_INNER] = y * sz;
        }
    }
}

// ---------------------------------------------------------------------------
extern "C" void kernel_launch(void* const* d_in, const int* in_sizes, int n_in,
                              void* d_out, int out_size, void* d_ws, size_t ws_size,
                              hipStream_t stream) {
    const float* x          = (const float*)d_in[0];
    const float* in_proj_w  = (const float*)d_in[1];
    const float* conv_w     = (const float*)d_in[2];
    const float* conv_b     = (const float*)d_in[3];
    const float* x_proj_w   = (const float*)d_in[4];
    const float* dt_proj_w  = (const float*)d_in[5];
    const float* dt_proj_b  = (const float*)d_in[6];
    const float* A_log      = (const float*)d_in[7];
    const float* Dvec       = (const float*)d_in[8];
    const float* out_proj_w = (const float*)d_in[9];
    float* out = (float*)d_out;

    float* xz     = (float*)d_ws;                          // 4096 x 4096
    float* xc_act = xz + (size_t)NROW * 2 * D_INNER;       // 4096 x 2048
    float* x_dbl  = xc_act + (size_t)NROW * D_INNER;       // 4096 x 96
    float* dlt    = x_dbl + (size_t)NROW * XPROJ_N;        // 4096 x 2048 (also y_gated)

    // 1) xz = x @ in_proj_w   (M=4096, N=4096, K=1024)
    gemm_f32<<<dim3(NROW / 128, (2 * D_INNER) / 128), 256, 0, stream>>>(
        x, in_proj_w, xz, NROW, 2 * D_INNER, D_MODEL);
    // 2) conv + silu  (consumes the xc half of xz; that half becomes scratch)
    conv_silu<<<(NROW * D_INNER) / 256, 256, 0, stream>>>(xz, conv_w, conv_b, xc_act);
    // 3) x_dbl = xc_act @ x_proj_w
    xdbl_gemm<<<NROW / 32, 256, 0, stream>>>(xc_act, x_proj_w, x_dbl);
    // 4) dlt = softplus(x_dbl[:, :64] @ dt_proj_w + b)
    dt_gemm<<<dim3(NROW / 64, D_INNER / 64), 256, 0, stream>>>(x_dbl, dt_proj_w, dt_proj_b, dlt);
    // 5) chunked selective scan (carries live in xz's dead xc-columns)
    scan_pass1<<<BATCH * NCHUNK * 8, 256, 0, stream>>>(dlt, xc_act, x_dbl, A_log, xz);
    scan_pass2<<<(BATCH * D_INNER * 16) / 256, 256, 0, stream>>>(xz);
    scan_pass3<<<BATCH * NCHUNK * 8, 256, 0, stream>>>(dlt, xc_act, x_dbl, xz,
                                                       A_log, Dvec, xz, dlt);
    // 6) out = y_gated @ out_proj_w  (M=4096, N=1024, K=2048)
    gemm_f32<<<dim3(NROW / 128, D_MODEL / 128), 256, 0, stream>>>(
        dlt, out_proj_w, out, NROW, D_MODEL, D_INNER);
}

// Round 4
// 470.167 us; speedup vs baseline: 4.8949x; 1.8465x over previous
//
#include <hip/hip_runtime.h>
#include <hip/hip_bf16.h>
#include <stdint.h>

#define D_MODEL 1024
#define D_STATE 16
#define D_CONV 4
#define D_INNER 2048
#define DT_RANK 64
#define BATCH 2
#define SEQ 2048
#define NROW (BATCH * SEQ)          // 4096
#define XPROJ_N (DT_RANK + 2 * D_STATE)  // 96
#define NCHUNK 64                   // time chunks for scan decomposition
#define CL 32                       // SEQ / NCHUNK

typedef __bf16 bf16x8 __attribute__((ext_vector_type(8)));
typedef float  f32x4  __attribute__((ext_vector_type(4)));

// RNE f32 -> bf16 (bit trick; inputs are tame, no NaN handling needed)
__device__ __forceinline__ uint16_t f2bf(float f) {
    uint32_t u = __float_as_uint(f);
    u += 0x7FFFu + ((u >> 16) & 1u);
    return (uint16_t)(u >> 16);
}
__device__ __forceinline__ float bf2f(uint16_t h) {
    return __uint_as_float((uint32_t)h << 16);
}

#define GLOAD_LDS(g, l) __builtin_amdgcn_global_load_lds(                      \
    (const __attribute__((address_space(1))) void*)(g),                        \
    (__attribute__((address_space(3))) void*)(l), 16, 0, 0)

// ---------------------------------------------------------------------------
// bf16 MFMA GEMM, m97 structure: C(MxN,f32) = A(MxK,bf16) @ B(KxN) with B
// given TRANSPOSED (BT is N x K). 128x128 tile, BK=32, 4 waves (2x2), each
// wave owns 64x64 = 4x4 fragments of 16x16. global_load_lds(16B) staging,
// ds_read_b128 fragment loads, mfma_f32_16x16x32_bf16.
// ---------------------------------------------------------------------------
__global__ __launch_bounds__(256) void gemm_bf16_bt(const uint16_t* __restrict__ A,
                                                    const uint16_t* __restrict__ BT,
                                                    float* __restrict__ C,
                                                    int M, int N, int K) {
    __shared__ uint16_t sA[128 * 32];   // [row][k], 64B rows
    __shared__ uint16_t sB[128 * 32];   // [n][k]
    const int tid  = threadIdx.x;
    const int wave = tid >> 6;          // 0..3
    const int lane = tid & 63;
    const int wm = wave >> 1, wn = wave & 1;
    const int bm = blockIdx.x * 128, bn = blockIdx.y * 128;

    // staging addresses: wave w covers tile rows [w*32, w*32+32) as two
    // 1024B segments; lane covers 16B: row = base + (lane>>2), col = (lane&3)*8
    const int lrow = lane >> 2;
    const int lcol = (lane & 3) * 8;
    const uint16_t* gA0 = A  + (size_t)(bm + wave * 32 + lrow) * K + lcol;
    const uint16_t* gA1 = gA0 + (size_t)16 * K;
    const uint16_t* gB0 = BT + (size_t)(bn + wave * 32 + lrow) * K + lcol;
    const uint16_t* gB1 = gB0 + (size_t)16 * K;
    uint16_t* lA0 = sA + (wave * 2 + 0) * 512;
    uint16_t* lA1 = sA + (wave * 2 + 1) * 512;
    uint16_t* lB0 = sB + (wave * 2 + 0) * 512;
    uint16_t* lB1 = sB + (wave * 2 + 1) * 512;

    const int fr = lane & 15;           // frag row (A: m-row, B: n-col)
    const int fg = lane >> 4;           // frag k-group (k = fg*8 + j)

    f32x4 acc[4][4] = {};

    for (int k0 = 0; k0 < K; k0 += 32) {
        GLOAD_LDS(gA0 + k0, lA0);
        GLOAD_LDS(gA1 + k0, lA1);
        GLOAD_LDS(gB0 + k0, lB0);
        GLOAD_LDS(gB1 + k0, lB1);
        __syncthreads();                 // drains vmcnt before barrier

        bf16x8 af[4], bfr[4];
#pragma unroll
        for (int m = 0; m < 4; ++m)
            af[m] = *(const bf16x8*)&sA[(wm * 64 + m * 16 + fr) * 32 + fg * 8];
#pragma unroll
        for (int n = 0; n < 4; ++n)
            bfr[n] = *(const bf16x8*)&sB[(wn * 64 + n * 16 + fr) * 32 + fg * 8];
#pragma unroll
        for (int m = 0; m < 4; ++m)
#pragma unroll
            for (int n = 0; n < 4; ++n)
                acc[m][n] = __builtin_amdgcn_mfma_f32_16x16x32_bf16(
                    af[m], bfr[n], acc[m][n], 0, 0, 0);
        __syncthreads();
    }

    // C/D layout: col = lane&15, row = (lane>>4)*4 + reg  [m89-verified]
#pragma unroll
    for (int m = 0; m < 4; ++m)
#pragma unroll
        for (int n = 0; n < 4; ++n) {
            const int col = bn + wn * 64 + n * 16 + fr;
#pragma unroll
            for (int r = 0; r < 4; ++r) {
                const int row = bm + wm * 64 + m * 16 + fg * 4 + r;
                C[(size_t)row * N + col] = acc[m][n][r];
            }
        }
}

// ---------------------------------------------------------------------------
// x (4096x1024 f32) -> A' (4096x3072 bf16) = [hi | lo | hi]
// ---------------------------------------------------------------------------
__global__ __launch_bounds__(256) void cvt_x_split(const float* __restrict__ x,
                                                   uint16_t* __restrict__ a1) {
    const int i = blockIdx.x * 256 + threadIdx.x;    // float4 index
    const int m = i >> 8;                            // 256 float4 per row
    const int c = (i & 255) << 2;
    const float4 v = ((const float4*)x)[i];
    uint16_t h[4], l[4];
    const float vf[4] = {v.x, v.y, v.z, v.w};
#pragma unroll
    for (int j = 0; j < 4; ++j) {
        h[j] = f2bf(vf[j]);
        l[j] = f2bf(vf[j] - bf2f(h[j]));
    }
    const size_t base = (size_t)m * 3072 + c;
    *(ushort4*)&a1[base]        = *(ushort4*)h;
    *(ushort4*)&a1[base + 1024] = *(ushort4*)l;
    *(ushort4*)&a1[base + 2048] = *(ushort4*)h;
}

// ---------------------------------------------------------------------------
// in_proj_w (1024x4096 f32) -> B'T (4096x3072 bf16): B'T[n][*] = [hi | hi | lo]
// of column n. 32x32 LDS transpose tiles.
// ---------------------------------------------------------------------------
__global__ __launch_bounds__(256) void cvt_wT_split(const float* __restrict__ w,
                                                    uint16_t* __restrict__ bt) {
    __shared__ float s[32][33];
    const int tid = threadIdx.x;
    const int k0 = blockIdx.x * 32;   // source row tile (K dim)
    const int n0 = blockIdx.y * 32;   // source col tile (N dim)
#pragma unroll
    for (int p = 0; p < 4; ++p) {
        int lin = tid + p * 256;
        int i = lin >> 5, j = lin & 31;
        s[i][j] = w[(size_t)(k0 + i) * 4096 + n0 + j];
    }
    __syncthreads();
    const int r = tid >> 3, c4 = (tid & 7) * 4;      // r: n-local, c4: k-local
    uint16_t h[4], l[4];
#pragma unroll
    for (int j = 0; j < 4; ++j) {
        float v = s[c4 + j][r];
        h[j] = f2bf(v);
        l[j] = f2bf(v - bf2f(h[j]));
    }
    const size_t base = (size_t)(n0 + r) * 3072 + k0 + c4;
    *(ushort4*)&bt[base]        = *(ushort4*)h;
    *(ushort4*)&bt[base + 1024] = *(ushort4*)h;
    *(ushort4*)&bt[base + 2048] = *(ushort4*)l;
}

// ---------------------------------------------------------------------------
// out_proj_w (2048x1024 f32) -> opwT (1024x2048 bf16), plain hi.
// ---------------------------------------------------------------------------
__global__ __launch_bounds__(256) void cvt_opwT(const float* __restrict__ w,
                                                uint16_t* __restrict__ bt) {
    __shared__ float s[32][33];
    const int tid = threadIdx.x;
    const int k0 = blockIdx.x * 32;   // source row tile (K=2048 dim)
    const int n0 = blockIdx.y * 32;   // source col tile (N=1024 dim)
#pragma unroll
    for (int p = 0; p < 4; ++p) {
        int lin = tid + p * 256;
        int i = lin >> 5, j = lin & 31;
        s[i][j] = w[(size_t)(k0 + i) * 1024 + n0 + j];
    }
    __syncthreads();
    const int r = tid >> 3, c4 = (tid & 7) * 4;
    uint16_t h[4];
#pragma unroll
    for (int j = 0; j < 4; ++j) h[j] = f2bf(s[c4 + j][r]);
    *(ushort4*)&bt[(size_t)(n0 + r) * 2048 + k0 + c4] = *(ushort4*)h;
}

// ---------------------------------------------------------------------------
// Causal depthwise conv (D_CONV=4) + bias + SiLU.
// ---------------------------------------------------------------------------
__global__ __launch_bounds__(256) void conv_silu(const float* __restrict__ xz,
                                                 const float* __restrict__ conv_w,
                                                 const float* __restrict__ conv_b,
                                                 float* __restrict__ xc_act) {
    int idx = blockIdx.x * 256 + threadIdx.x;       // over NROW*D_INNER
    int d = idx & (D_INNER - 1);
    int r = idx >> 11;                               // b*SEQ + t
    int t = r & (SEQ - 1);
    float acc = conv_b[d];
#pragma unroll
    for (int k = 0; k < D_CONV; ++k) {
        int tt = t + k - (D_CONV - 1);
        if (tt >= 0)
            acc = fmaf(xz[(size_t)(r + k - (D_CONV - 1)) * (2 * D_INNER) + d],
                       conv_w[d * D_CONV + k], acc);
    }
    float s = acc / (1.f + __expf(-acc));            // silu
    xc_act[(size_t)r * D_INNER + d] = s;
}

// ---------------------------------------------------------------------------
// x_dbl = xc_act (NROW x D_INNER) @ x_proj_w (D_INNER x 96). BM=32, full N=96.
// ---------------------------------------------------------------------------
__global__ __launch_bounds__(256) void xdbl_gemm(const float* __restrict__ A,
                                                 const float* __restrict__ W,
                                                 float* __restrict__ out) {
    __shared__ float As[32][132];    // [row][k], +4 pad
    __shared__ float Ws[128][96];    // [k][col]
    const int tid = threadIdx.x;
    const int bm = blockIdx.x * 32;
    const int tc = tid & 31;         // cols tc*3 .. +2
    const int tr = tid >> 5;         // rows tr*4 .. +3
    float acc[4][3];
#pragma unroll
    for (int i = 0; i < 4; ++i)
#pragma unroll
        for (int j = 0; j < 3; ++j) acc[i][j] = 0.f;

    for (int k0 = 0; k0 < D_INNER; k0 += 128) {
#pragma unroll
        for (int l = 0; l < 4; ++l) {                 // A tile 32x128
            int i = tid + l * 256;
            int r = i >> 5, c4 = (i & 31) << 2;
            *(float4*)&As[r][c4] = *(const float4*)(A + (size_t)(bm + r) * D_INNER + k0 + c4);
        }
#pragma unroll
        for (int l = 0; l < 12; ++l) {                // W tile 128x96
            int i = tid + l * 256;
            int r = i / 24, c4 = (i % 24) << 2;
            *(float4*)&Ws[r][c4] = *(const float4*)(W + (size_t)(k0 + r) * XPROJ_N + c4);
        }
        __syncthreads();
#pragma unroll 8
        for (int k = 0; k < 128; ++k) {
            float a0 = As[tr * 4 + 0][k], a1 = As[tr * 4 + 1][k];
            float a2 = As[tr * 4 + 2][k], a3 = As[tr * 4 + 3][k];
            float w0 = Ws[k][tc * 3 + 0], w1 = Ws[k][tc * 3 + 1], w2 = Ws[k][tc * 3 + 2];
            acc[0][0] = fmaf(a0, w0, acc[0][0]); acc[0][1] = fmaf(a0, w1, acc[0][1]); acc[0][2] = fmaf(a0, w2, acc[0][2]);
            acc[1][0] = fmaf(a1, w0, acc[1][0]); acc[1][1] = fmaf(a1, w1, acc[1][1]); acc[1][2] = fmaf(a1, w2, acc[1][2]);
            acc[2][0] = fmaf(a2, w0, acc[2][0]); acc[2][1] = fmaf(a2, w1, acc[2][1]); acc[2][2] = fmaf(a2, w2, acc[2][2]);
            acc[3][0] = fmaf(a3, w0, acc[3][0]); acc[3][1] = fmaf(a3, w1, acc[3][1]); acc[3][2] = fmaf(a3, w2, acc[3][2]);
        }
        __syncthreads();
    }
#pragma unroll
    for (int i = 0; i < 4; ++i)
#pragma unroll
        for (int j = 0; j < 3; ++j)
            out[(size_t)(bm + tr * 4 + i) * XPROJ_N + tc * 3 + j] = acc[i][j];
}

// ---------------------------------------------------------------------------
// dlt = softplus(x_dbl[:, :64] @ dt_proj_w + dt_proj_b).  K=64, tiles 64x64.
// ---------------------------------------------------------------------------
__global__ __launch_bounds__(256) void dt_gemm(const float* __restrict__ xdbl,
                                               const float* __restrict__ W,
                                               const float* __restrict__ bias,
                                               float* __restrict__ out) {
    __shared__ float As[64][68];     // [q][row], +4 pad
    __shared__ float Ws[64][64];     // [q][col]
    const int tid = threadIdx.x;
    const int bm = blockIdx.x * 64, bn = blockIdx.y * 64;
#pragma unroll
    for (int l = 0; l < 4; ++l) {    // A: 64 rows x 64 q
        int i = tid + l * 256;
        int r = i >> 4, q4 = (i & 15) << 2;
        float4 v = *(const float4*)(xdbl + (size_t)(bm + r) * XPROJ_N + q4);
        As[q4 + 0][r] = v.x; As[q4 + 1][r] = v.y; As[q4 + 2][r] = v.z; As[q4 + 3][r] = v.w;
    }
#pragma unroll
    for (int l = 0; l < 4; ++l) {    // W: 64 q x 64 cols
        int i = tid + l * 256;
        int q = i >> 4, c4 = (i & 15) << 2;
        *(float4*)&Ws[q][c4] = *(const float4*)(W + (size_t)q * D_INNER + bn + c4);
    }
    __syncthreads();
    const int tx = tid & 15, ty = tid >> 4;
    float acc[4][4];
#pragma unroll
    for (int i = 0; i < 4; ++i)
#pragma unroll
        for (int j = 0; j < 4; ++j) acc[i][j] = 0.f;
#pragma unroll 16
    for (int k = 0; k < 64; ++k) {
        float a[4], w[4];
        *(float4*)a = *(const float4*)&As[k][ty * 4];
        *(float4*)w = *(const float4*)&Ws[k][tx * 4];
#pragma unroll
        for (int i = 0; i < 4; ++i)
#pragma unroll
            for (int j = 0; j < 4; ++j)
                acc[i][j] = fmaf(a[i], w[j], acc[i][j]);
    }
#pragma unroll
    for (int i = 0; i < 4; ++i) {
#pragma unroll
        for (int j = 0; j < 4; ++j) {
            float v = acc[i][j] + bias[bn + tx * 4 + j];
            float sp = fmaxf(v, 0.f) + log1pf(__expf(-fabsf(v)));
            out[(size_t)(bm + ty * 4 + i) * D_INNER + bn + tx * 4 + j] = sp;
        }
    }
}

// ---------------------------------------------------------------------------
// Chunked selective scan; carries live in the dead xc-half of xz.
//   hole(i) = (i>>11)*4096 + (i&2047)
// ---------------------------------------------------------------------------
__device__ __forceinline__ size_t hole(size_t i) {
    return (i >> 11) * 4096 + (i & 2047);
}

__global__ __launch_bounds__(256) void scan_pass1(const float* __restrict__ dlt,
                                                  const float* __restrict__ xc,
                                                  const float* __restrict__ xdbl,
                                                  const float* __restrict__ A_log,
                                                  float* __restrict__ carry) {
    __shared__ float s_B[CL][16];
    const int tid = threadIdx.x;
    const int bid = blockIdx.x;              // b*512 + c*8 + dg
    const int dg = bid & 7;
    const int c  = (bid >> 3) & (NCHUNK - 1);
    const int b  = bid >> 9;
    const int d  = dg * 256 + tid;
    const size_t rowbase = (size_t)b * SEQ + c * CL;

    float An[16];
    {
        float tmp[16];
        *(float4*)&tmp[0]  = *(const float4*)&A_log[d * 16 + 0];
        *(float4*)&tmp[4]  = *(const float4*)&A_log[d * 16 + 4];
        *(float4*)&tmp[8]  = *(const float4*)&A_log[d * 16 + 8];
        *(float4*)&tmp[12] = *(const float4*)&A_log[d * 16 + 12];
#pragma unroll
        for (int n = 0; n < 16; ++n) An[n] = -__expf(tmp[n]);
    }

#pragma unroll
    for (int p = 0; p < CL * 16 / 256; ++p) {
        int i = tid + p * 256;
        int t = i >> 4, n = i & 15;
        s_B[t][n] = xdbl[(rowbase + t) * (size_t)XPROJ_N + DT_RANK + n];
    }
    __syncthreads();

    float h[16], pA[16];
#pragma unroll
    for (int n = 0; n < 16; ++n) { h[n] = 0.f; pA[n] = 1.f; }

    const float* dtp = dlt + rowbase * D_INNER + d;
    const float* xvp = xc + rowbase * D_INNER + d;

    for (int tb = 0; tb < CL; tb += 4) {
        float dtv[4], xvv[4];
#pragma unroll
        for (int s = 0; s < 4; ++s) {
            dtv[s] = dtp[(size_t)(tb + s) * D_INNER];
            xvv[s] = xvp[(size_t)(tb + s) * D_INNER];
        }
#pragma unroll
        for (int s = 0; s < 4; ++s) {
            float Bv[16];
            *(float4*)&Bv[0]  = *(const float4*)&s_B[tb + s][0];
            *(float4*)&Bv[4]  = *(const float4*)&s_B[tb + s][4];
            *(float4*)&Bv[8]  = *(const float4*)&s_B[tb + s][8];
            *(float4*)&Bv[12] = *(const float4*)&s_B[tb + s][12];
            float du = dtv[s] * xvv[s];
#pragma unroll
            for (int n = 0; n < 16; ++n) {
                float dA = __expf(dtv[s] * An[n]);
                pA[n] *= dA;
                h[n] = fmaf(dA, h[n], du * Bv[n]);
            }
        }
    }

    size_t ci = (((size_t)b * NCHUNK + c) * D_INNER + d) * 16;
    float* pp = carry + hole(ci);
    float* hp = carry + hole(ci + ((size_t)1 << 22));
    *(float4*)&pp[0]  = *(float4*)&pA[0];  *(float4*)&pp[4]  = *(float4*)&pA[4];
    *(float4*)&pp[8]  = *(float4*)&pA[8];  *(float4*)&pp[12] = *(float4*)&pA[12];
    *(float4*)&hp[0]  = *(float4*)&h[0];   *(float4*)&hp[4]  = *(float4*)&h[4];
    *(float4*)&hp[8]  = *(float4*)&h[8];   *(float4*)&hp[12] = *(float4*)&h[12];
}

__global__ __launch_bounds__(256) void scan_pass2(float* __restrict__ carry) {
    int idx = blockIdx.x * 256 + threadIdx.x;        // over B*D*16 = 65536
    int n = idx & 15;
    int d = (idx >> 4) & (D_INNER - 1);
    int b = idx >> 15;
    float prev = 0.f;
    for (int c = 0; c < NCHUNK; ++c) {
        size_t ci = (((size_t)b * NCHUNK + c) * D_INNER + d) * 16 + n;
        size_t op = hole(ci);
        size_t oh = op + (size_t)2048 * 4096;
        float p = carry[op];
        float e = carry[oh];
        carry[oh] = prev;
        prev = fmaf(p, prev, e);
    }
}

// pass 3: re-run chunk with true h_in; y = <h,C> + xv*D; gate; write BF16.
__global__ __launch_bounds__(256) void scan_pass3(const float* __restrict__ dlt,
                                                  const float* __restrict__ xc,
                                                  const float* __restrict__ xdbl,
                                                  const float* __restrict__ xz,
                                                  const float* __restrict__ A_log,
                                                  const float* __restrict__ Dvec,
                                                  const float* __restrict__ carry,
                                                  uint16_t* __restrict__ ygb) {
    __shared__ float s_B[CL][16];
    __shared__ float s_C[CL][16];
    const int tid = threadIdx.x;
    const int bid = blockIdx.x;
    const int dg = bid & 7;
    const int c  = (bid >> 3) & (NCHUNK - 1);
    const int b  = bid >> 9;
    const int d  = dg * 256 + tid;
    const size_t rowbase = (size_t)b * SEQ + c * CL;

    float An[16];
    {
        float tmp[16];
        *(float4*)&tmp[0]  = *(const float4*)&A_log[d * 16 + 0];
        *(float4*)&tmp[4]  = *(const float4*)&A_log[d * 16 + 4];
        *(float4*)&tmp[8]  = *(const float4*)&A_log[d * 16 + 8];
        *(float4*)&tmp[12] = *(const float4*)&A_log[d * 16 + 12];
#pragma unroll
        for (int n = 0; n < 16; ++n) An[n] = -__expf(tmp[n]);
    }
    const float Dd = Dvec[d];

#pragma unroll
    for (int p = 0; p < CL * 32 / 256; ++p) {
        int i = tid + p * 256;
        int t = i >> 5, col = i & 31;
        float v = xdbl[(rowbase + t) * (size_t)XPROJ_N + DT_RANK + col];
        if (col < 16) s_B[t][col] = v;
        else          s_C[t][col - 16] = v;
    }
    __syncthreads();

    float h[16];
    {
        size_t ci = (((size_t)b * NCHUNK + c) * D_INNER + d) * 16;
        const float* hp = carry + hole(ci + ((size_t)1 << 22));
        *(float4*)&h[0]  = *(const float4*)&hp[0];
        *(float4*)&h[4]  = *(const float4*)&hp[4];
        *(float4*)&h[8]  = *(const float4*)&hp[8];
        *(float4*)&h[12] = *(const float4*)&hp[12];
    }

    const float* dtp = dlt + rowbase * D_INNER + d;
    const float* xvp = xc + rowbase * D_INNER + d;
    const float* zp  = xz + rowbase * (size_t)(2 * D_INNER) + D_INNER + d;
    uint16_t* yp = ygb + rowbase * D_INNER + d;

    for (int tb = 0; tb < CL; tb += 4) {
        float dtv[4], xvv[4], zv[4];
#pragma unroll
        for (int s = 0; s < 4; ++s) {
            dtv[s] = dtp[(size_t)(tb + s) * D_INNER];
            xvv[s] = xvp[(size_t)(tb + s) * D_INNER];
            zv[s]  = zp[(size_t)(tb + s) * (2 * D_INNER)];
        }
#pragma unroll
        for (int s = 0; s < 4; ++s) {
            float Bv[16], Cv[16];
            *(float4*)&Bv[0]  = *(const float4*)&s_B[tb + s][0];
            *(float4*)&Bv[4]  = *(const float4*)&s_B[tb + s][4];
            *(float4*)&Bv[8]  = *(const float4*)&s_B[tb + s][8];
            *(float4*)&Bv[12] = *(const float4*)&s_B[tb + s][12];
            *(float4*)&Cv[0]  = *(const float4*)&s_C[tb + s][0];
            *(float4*)&Cv[4]  = *(const float4*)&s_C[tb + s][4];
            *(float4*)&Cv[8]  = *(const float4*)&s_C[tb + s][8];
            *(float4*)&Cv[12] = *(const float4*)&s_C[tb + s][12];
            float du = dtv[s] * xvv[s];
            float y = 0.f;
#pragma unroll
            for (int n = 0; n < 16; ++n) {
                float dA = __expf(dtv[s] * An[n]);
                h[n] = fmaf(dA, h[n], du * Bv[n]);
                y = fmaf(h[n], Cv[n], y);
            }
            y = fmaf(xvv[s], Dd, y);
            float sz = zv[s] / (1.f + __expf(-zv[s]));
            yp[(size_t)(tb + s) * D_INNER] = f2bf(y * sz);
        }
    }
}

// ---------------------------------------------------------------------------
extern "C" void kernel_launch(void* const* d_in, const int* in_sizes, int n_in,
                              void* d_out, int out_size, void* d_ws, size_t ws_size,
                              hipStream_t stream) {
    const float* x          = (const float*)d_in[0];
    const float* in_proj_w  = (const float*)d_in[1];
    const float* conv_w     = (const float*)d_in[2];
    const float* conv_b     = (const float*)d_in[3];
    const float* x_proj_w   = (const float*)d_in[4];
    const float* dt_proj_w  = (const float*)d_in[5];
    const float* dt_proj_b  = (const float*)d_in[6];
    const float* A_log      = (const float*)d_in[7];
    const float* Dvec       = (const float*)d_in[8];
    const float* out_proj_w = (const float*)d_in[9];
    float* out = (float*)d_out;

    // f32 workspace regions
    float* xz     = (float*)d_ws;                          // 16,777,216 f (64MB)
    float* xc_act = xz + (size_t)NROW * 2 * D_INNER;       //  8,388,608 f (32MB)
    float* x_dbl  = xc_act + (size_t)NROW * D_INNER;       //    393,216 f (1.5MB)
    float* dlt    = x_dbl + (size_t)NROW * XPROJ_N;        //  8,388,608 f (32MB)
    // bf16 aliases with disjoint lifetimes:
    uint16_t* A1   = (uint16_t*)xc_act;                    // 24MB, dead before conv_silu
    uint16_t* B1T  = (uint16_t*)x_dbl;                     // 24MB, dead before xdbl_gemm
    uint16_t* ygb  = (uint16_t*)(dlt + (size_t)NROW * D_INNER);  // 16MB fresh
    uint16_t* opwT = ygb + (size_t)NROW * D_INNER;               //  4MB fresh

    // 1) split-bf16 operand prep for GEMM1
    cvt_x_split<<<(NROW * D_MODEL / 4) / 256, 256, 0, stream>>>(x, A1);
    cvt_wT_split<<<dim3(D_MODEL / 32, (2 * D_INNER) / 32), 256, 0, stream>>>(in_proj_w, B1T);
    // 2) xz = x @ in_proj_w  via bf16 MFMA, K' = 3*1024 (exact hi/lo split)
    gemm_bf16_bt<<<dim3(NROW / 128, (2 * D_INNER) / 128), 256, 0, stream>>>(
        A1, B1T, xz, NROW, 2 * D_INNER, 3 * D_MODEL);
    // 3) conv + silu (A1's region becomes xc_act here)
    conv_silu<<<(NROW * D_INNER) / 256, 256, 0, stream>>>(xz, conv_w, conv_b, xc_act);
    // 4) x_dbl = xc_act @ x_proj_w (clobbers head of dead B1T)
    xdbl_gemm<<<NROW / 32, 256, 0, stream>>>(xc_act, x_proj_w, x_dbl);
    // 5) dlt = softplus(x_dbl[:, :64] @ dt_proj_w + b)
    dt_gemm<<<dim3(NROW / 64, D_INNER / 64), 256, 0, stream>>>(x_dbl, dt_proj_w, dt_proj_b, dlt);
    // 6) chunked selective scan; pass3 writes y_gated directly as bf16
    scan_pass1<<<BATCH * NCHUNK * 8, 256, 0, stream>>>(dlt, xc_act, x_dbl, A_log, xz);
    scan_pass2<<<(BATCH * D_INNER * 16) / 256, 256, 0, stream>>>(xz);
    scan_pass3<<<BATCH * NCHUNK * 8, 256, 0, stream>>>(dlt, xc_act, x_dbl, xz,
                                                       A_log, Dvec, xz, ygb);
    // 7) out-projection operand prep + bf16 GEMM2
    cvt_opwT<<<dim3(D_INNER / 32, D_MODEL / 32), 256, 0, stream>>>(out_proj_w, opwT);
    gemm_bf16_bt<<<dim3(NROW / 128, D_MODEL / 128), 256, 0, stream>>>(
        ygb, opwT, out, NROW, D_MODEL, D_INNER);
}